// Round 22
// baseline (248.604 us; speedup 1.0000x reference)
//
#include <hip/hip_runtime.h>
#include <hip/hip_bf16.h>
#include <stdint.h>

// Problem constants (GroupedQueryAttention: B=2,S=2048,D=1024,H=16,KVH=4)
#define B_    2
#define S_    2048
#define D_    1024
#define H_    16
#define KVH_  4
#define HD_   64
#define REP_  4
#define BS_   (B_ * S_)        // 4096 tokens
#define KVD_  256
#define QKVS_ 1536             // fused QKV row stride: Q(1024) | K(256) | V(256)
#define NTT_  (S_ / 128)       // 16 KV tiles of 128
#define VSPLIT_ (D_ + KVD_)    // 1280: V columns start here (block-aligned)

typedef unsigned short u16;
typedef short s16x4 __attribute__((ext_vector_type(4)));
typedef short s16x8 __attribute__((ext_vector_type(8)));
typedef float f32x4 __attribute__((ext_vector_type(4)));

typedef const __attribute__((address_space(1))) void* gvp;
typedef __attribute__((address_space(3))) void* lvp;

#define MFMA16(a, b, c) __builtin_amdgcn_mfma_f32_16x16x32_bf16((a), (b), (c), 0, 0, 0)

__device__ __forceinline__ u16 f2b(float f) {  // RNE f32->bf16 (finite inputs)
  uint32_t u = __float_as_uint(f);
  u += 0x7fffu + ((u >> 16) & 1u);
  return (u16)(u >> 16);
}

// XOR swizzles: 64-wide rows (8 x 16B slots) and 128-wide rows (16 slots).
__device__ __forceinline__ int swz64(int row, int slot) {
  return slot ^ (row & 7) ^ ((row >> 3) & 7);
}
__device__ __forceinline__ int swz128(int row, int slot) {
  return slot ^ (row & 15);
}

// ---------------- fused f32 -> bf16 conversion over 5 segments ----------------
#define N0_ (BS_ * D_ / 4)
#define N1_ (D_ * D_ / 4)
#define N2_ (KVD_ * D_ / 4)
__global__ void cvt5_kernel(const float* __restrict__ s0, const float* __restrict__ s1,
                            const float* __restrict__ s2, const float* __restrict__ s3,
                            const float* __restrict__ s4, u16* __restrict__ dst, int n4tot) {
  for (int i = blockIdx.x * blockDim.x + threadIdx.x; i < n4tot;
       i += gridDim.x * blockDim.x) {
    const float* src;
    int j = i;
    if (j < N0_) src = s0;
    else if ((j -= N0_) < N1_) src = s1;
    else if ((j -= N1_) < N2_) src = s2;
    else if ((j -= N2_) < N2_) src = s3;
    else { j -= N2_; src = s4; }
    const float4 v = reinterpret_cast<const float4*>(src)[j];
    uint2 o;
    o.x = (uint32_t)f2b(v.x) | ((uint32_t)f2b(v.y) << 16);
    o.y = (uint32_t)f2b(v.z) | ((uint32_t)f2b(v.w) << 16);
    reinterpret_cast<uint2*>(dst)[i] = o;
  }
}

// ---------------- bf16 GEMM, C = A(MxK) * B(NxK)^T, 64x128 tile, BK=64 ----------------
// Double-buffered staging; swz64 both-sides LDS swizzle; XCD-bijective grid.
// WRITE_VT: V-columns (>= VSPLIT_) written TRANSPOSED to VT (fused vtrans).
template <int OUT_BF16, int WRITE_VT>
__global__ __launch_bounds__(256) void gemm64(const u16* __restrict__ A,
                                              const u16* __restrict__ Bw,
                                              void* __restrict__ Cout,
                                              u16* __restrict__ VT,
                                              int M, int N, int K) {
  __shared__ u16 As[2][64 * 64];
  __shared__ u16 Bs[2][128 * 64];
  const int tid = threadIdx.x;
  const int lane = tid & 63;
  const int wid = tid >> 6;
  const int l16 = lane & 15;
  const int kq = lane >> 4;
  // XCD swizzle: hw-blocks on one XCD (bid0 mod 8) get a contiguous logical chunk
  const int nwg = gridDim.x * gridDim.y;
  const int bid0 = blockIdx.y * gridDim.x + blockIdx.x;
  const int bid = (bid0 & 7) * (nwg >> 3) + (bid0 >> 3);
  const int bm = (bid / gridDim.x) * 64;
  const int bn = (bid % gridDim.x) * 128;
  const int wr = (wid >> 1) * 32;
  const int wc = (wid & 1) * 64;

  // staging geometry (pre-swizzled source cols, linear LDS dst)
  int arow[2], acol[2], brow[4], bcol[4], sdst[4];
#pragma unroll
  for (int i = 0; i < 4; ++i) {
    const int e = (i * 256 + tid) * 8;
    const int row = e >> 6;
    const int col = swz64(row, (e >> 3) & 7) * 8;
    sdst[i] = e;
    if (i < 2) { arow[i] = row; acol[i] = col; }
    brow[i] = row;
    bcol[i] = col;
  }
  // frag read offsets (involution)
  int aoff[2][2], boff[4][2];
#pragma unroll
  for (int m = 0; m < 2; ++m)
#pragma unroll
    for (int kk = 0; kk < 2; ++kk) {
      const int row = wr + m * 16 + l16;
      aoff[m][kk] = row * 64 + swz64(row, kk * 4 + kq) * 8;
    }
#pragma unroll
  for (int n = 0; n < 4; ++n)
#pragma unroll
    for (int kk = 0; kk < 2; ++kk) {
      const int row = wc + n * 16 + l16;
      boff[n][kk] = row * 64 + swz64(row, kk * 4 + kq) * 8;
    }

  auto stage = [&](int buf, int kt) {
#pragma unroll
    for (int i = 0; i < 2; ++i)
      __builtin_amdgcn_global_load_lds((gvp)(A + (size_t)(bm + arow[i]) * K + kt + acol[i]),
                                       (lvp)(&As[buf][sdst[i]]), 16, 0, 0);
#pragma unroll
    for (int i = 0; i < 4; ++i)
      __builtin_amdgcn_global_load_lds((gvp)(Bw + (size_t)(bn + brow[i]) * K + kt + bcol[i]),
                                       (lvp)(&Bs[buf][sdst[i]]), 16, 0, 0);
  };

  f32x4 acc[2][4] = {};
  stage(0, 0);
  int cur = 0;

  for (int kt = 0; kt < K; kt += 64) {
    __syncthreads();                   // buf[cur] ready (drains in-flight loads)
    if (kt + 64 < K) stage(cur ^ 1, kt + 64);

#pragma unroll
    for (int kk = 0; kk < 2; ++kk) {
      s16x8 af[2], bfr[4];
#pragma unroll
      for (int m = 0; m < 2; ++m)
        af[m] = *reinterpret_cast<const s16x8*>(&As[cur][aoff[m][kk]]);
#pragma unroll
      for (int n = 0; n < 4; ++n)
        bfr[n] = *reinterpret_cast<const s16x8*>(&Bs[cur][boff[n][kk]]);
#pragma unroll
      for (int m = 0; m < 2; ++m)
#pragma unroll
        for (int n = 0; n < 4; ++n)
          acc[m][n] = MFMA16(af[m], bfr[n], acc[m][n]);
    }
    cur ^= 1;
  }

  if (WRITE_VT && bn >= VSPLIT_) {
    // V block: write transposed to VT[((b*4+g)*64+d)][s]; 4 consecutive tokens
    // per (m,n) = 8B contiguous store.
#pragma unroll
    for (int m = 0; m < 2; ++m) {
      const int row0 = bm + wr + m * 16 + kq * 4;   // token row (4 consecutive)
      const int b = row0 >> 11;
      const int s = row0 & (S_ - 1);
#pragma unroll
      for (int n = 0; n < 4; ++n) {
        const int off = bn - VSPLIT_ + wc + n * 16 + l16;
        const int g = off >> 6;
        const int d = off & 63;
        uint2 o;
        o.x = (uint32_t)f2b(acc[m][n][0]) | ((uint32_t)f2b(acc[m][n][1]) << 16);
        o.y = (uint32_t)f2b(acc[m][n][2]) | ((uint32_t)f2b(acc[m][n][3]) << 16);
        *reinterpret_cast<uint2*>(&VT[((size_t)(b * 4 + g) * 64 + d) * S_ + s]) = o;
      }
    }
    return;
  }

#pragma unroll
  for (int m = 0; m < 2; ++m) {
    const int row0 = bm + wr + m * 16 + kq * 4;
#pragma unroll
    for (int n = 0; n < 4; ++n) {
      const int col = bn + wc + n * 16 + l16;
#pragma unroll
      for (int r = 0; r < 4; ++r) {
        if (OUT_BF16) {
          ((u16*)Cout)[(size_t)(row0 + r) * N + col] = f2b(acc[m][n][r]);
        } else {
          ((float*)Cout)[(size_t)(row0 + r) * N + col] = acc[m][n][r];
        }
      }
    }
  }
}

// ---------------- flash attention (GQA): zero-shuffle PV, KVBLK=128, 8 waves ----------------
// 512 thr = 8 waves: wave w = (q-sub w>>2, head g*4+(w&3)), 64 q-rows/block.
// Same per-wave tile body as r21; K/V staging shared by 8 waves -> grid 256
// blocks, 2 blocks/CU, 16 waves/CU = 4 waves/SIMD (2x occupancy).
__global__ __launch_bounds__(512, 4) void attn_kernel(const u16* __restrict__ QKV,
                                                      const u16* __restrict__ VT,
                                                      const int* __restrict__ mask,
                                                      u16* __restrict__ O) {
  __shared__ u16 Ks[2][128 * 64];      // K rows, 64-wide swizzled
  __shared__ u16 Vt[2][64 * 128];      // V^T rows (d), 128-wide swizzled

  const int tid = threadIdx.x;
  const int lane = tid & 63;
  const int wid = tid >> 6;            // 0..7
  const int l16 = lane & 15;
  const int kq = lane >> 4;            // 0..3
  const int bg = blockIdx.y;
  const int b = bg >> 2;               // / KVH
  const int g = bg & 3;
  const int h = g * REP_ + (wid & 3);
  const int q0 = blockIdx.x * 64 + (wid >> 2) * 32;
  const u16* kv_base = QKV + (size_t)b * S_ * QKVS_ + D_ + g * HD_;  // K cols
  const u16* vt_base = VT + (size_t)bg * 64 * S_;                     // V^T rows
  const int* maskp = mask + b * S_ + lane;
  const float Cs = 0.18033688011112042f;  // SCALE * log2(e)

  // ---- precomputed per-thread LDS element offsets (loop-invariant) ----
  int koff[8][2];
#pragma unroll
  for (int n = 0; n < 8; ++n)
#pragma unroll
    for (int c = 0; c < 2; ++c) {
      const int row = n * 16 + l16;
      koff[n][c] = row * 64 + swz64(row, c * 4 + kq) * 8;
    }
  const int hs = kq >> 1;
  const int bo = 4 * (kq & 1);
  int vbase[8];                        // voff = vbase[j] + m*2048  (drow&15 == l16)
#pragma unroll
  for (int c = 0; c < 4; ++c) {
    vbase[2 * c] = l16 * 128 + swz128(l16, 4 * c + hs) * 8 + bo;
    vbase[2 * c + 1] = l16 * 128 + swz128(l16, 4 * c + 2 + hs) * 8 + bo;
  }
  // staging: 512 threads x 2 iters x 8 elems = 8192 elems per buffer
  int kst_src[2], vst_src[2], st_dst[2];
#pragma unroll
  for (int i = 0; i < 2; ++i) {
    const int e = (i * 512 + tid) * 8;
    st_dst[i] = e;
    const int krow = e >> 6;
    kst_src[i] = krow * QKVS_ + swz64(krow, (e >> 3) & 7) * 8;   // + kv0*QKVS_
    const int vrow = e >> 7;
    vst_src[i] = vrow * S_ + swz128(vrow, (e >> 3) & 15) * 8;    // + kv0
  }

  auto kstage = [&](int buf, int kv0) {
#pragma unroll
    for (int i = 0; i < 2; ++i)
      __builtin_amdgcn_global_load_lds(
          (gvp)(kv_base + (size_t)kv0 * QKVS_ + kst_src[i]),
          (lvp)(&Ks[buf][st_dst[i]]), 16, 0, 0);
  };
  auto vstage = [&](int buf, int kv0) {
#pragma unroll
    for (int i = 0; i < 2; ++i)
      __builtin_amdgcn_global_load_lds(
          (gvp)(vt_base + kv0 + vst_src[i]),
          (lvp)(&Vt[buf][st_dst[i]]), 16, 0, 0);
  };

  // Q B-frags: qf[g2][c] = Q[q0+g2*16+l16][c*32+kq*8..]
  s16x8 qf[2][2];
#pragma unroll
  for (int g2 = 0; g2 < 2; ++g2) {
    const u16* qp = QKV + (size_t)(b * S_ + q0 + g2 * 16 + l16) * QKVS_ + h * HD_ + kq * 8;
    qf[g2][0] = *reinterpret_cast<const s16x8*>(qp);
    qf[g2][1] = *reinterpret_cast<const s16x8*>(qp + 32);
  }

  // prologue: stage tile 0 into buf 0; mask tile 0 into regs
  kstage(0, 0);
  vstage(0, 0);
  int mcur0 = maskp[0];
  int mcur1 = maskp[64];

  float m_run[2] = {-1e30f, -1e30f}, l_run[2] = {0.f, 0.f};
  f32x4 acc[2][4] = {};                // O^T per group: row d=m*16+kq*4+r, col q=l16

#define ATTN_TILE(T_, BUF_)                                                       \
  {                                                                               \
    const int t_ = (T_);                                                          \
    __syncthreads();                                                              \
    const bool pfch = (t_ + 1 < NTT_);                                            \
    int mnext0 = 0, mnext1 = 0;                                                   \
    if (pfch) {                                                                   \
      kstage((BUF_) ^ 1, (t_ + 1) * 128);                                         \
      vstage((BUF_) ^ 1, (t_ + 1) * 128);                                         \
      mnext0 = maskp[(t_ + 1) * 128];                                             \
      mnext1 = maskp[(t_ + 1) * 128 + 64];                                        \
    }                                                                             \
    const u16* ks = &Ks[(BUF_)][0];                                               \
    const u16* vt = &Vt[(BUF_)][0];                                               \
    f32x4 sc[2][8];                                                               \
    __builtin_amdgcn_s_setprio(1);                                                \
    _Pragma("unroll") for (int n = 0; n < 8; ++n) {                               \
      const s16x8 kf0 = *reinterpret_cast<const s16x8*>(ks + koff[n][0]);         \
      const s16x8 kf1 = *reinterpret_cast<const s16x8*>(ks + koff[n][1]);         \
      f32x4 s0 = {0.f, 0.f, 0.f, 0.f};                                            \
      f32x4 s1 = {0.f, 0.f, 0.f, 0.f};                                            \
      s0 = MFMA16(kf0, qf[0][0], s0);                                             \
      s1 = MFMA16(kf0, qf[1][0], s1);                                             \
      s0 = MFMA16(kf1, qf[0][1], s0);                                             \
      s1 = MFMA16(kf1, qf[1][1], s1);                                             \
      sc[0][n] = s0;                                                              \
      sc[1][n] = s1;                                                              \
    }                                                                             \
    __builtin_amdgcn_s_setprio(0);                                                \
    const unsigned long long mb0 = __ballot(mcur0 != 0);                          \
    const unsigned long long mb1 = __ballot(mcur1 != 0);                          \
    if ((~mb0) | (~mb1)) {                                                        \
      _Pragma("unroll") for (int n = 0; n < 8; ++n) {                             \
        const unsigned long long mb = (n < 4) ? mb0 : mb1;                        \
        const int sh = (n & 3) * 16 + kq * 4;                                     \
        _Pragma("unroll") for (int r = 0; r < 4; ++r) {                           \
          if (!((mb >> (sh + r)) & 1ull)) {                                       \
            sc[0][n][r] = -3.0e38f;                                               \
            sc[1][n][r] = -3.0e38f;                                               \
          }                                                                       \
        }                                                                         \
      }                                                                           \
    }                                                                             \
    union PK { uint32_t u[16]; s16x8 v[4]; } pk[2];                               \
    _Pragma("unroll") for (int g2 = 0; g2 < 2; ++g2) {                            \
      f32x4 tv = sc[g2][0];                                                       \
      _Pragma("unroll") for (int n = 1; n < 8; ++n) {                             \
        tv[0] = fmaxf(tv[0], sc[g2][n][0]);                                       \
        tv[1] = fmaxf(tv[1], sc[g2][n][1]);                                       \
        tv[2] = fmaxf(tv[2], sc[g2][n][2]);                                       \
        tv[3] = fmaxf(tv[3], sc[g2][n][3]);                                       \
      }                                                                           \
      float tm = fmaxf(fmaxf(tv[0], tv[1]), fmaxf(tv[2], tv[3]));                 \
      tm = fmaxf(tm, __shfl_xor(tm, 16));                                         \
      tm = fmaxf(tm, __shfl_xor(tm, 32));                                         \
      if (!__all(tm <= m_run[g2] + 44.0f)) {                                      \
        const float mnew = fmaxf(m_run[g2], tm);                                  \
        const float fac = exp2f((m_run[g2] - mnew) * Cs);                         \
        m_run[g2] = mnew;                                                         \
        l_run[g2] *= fac;                                                         \
        _Pragma("unroll") for (int m = 0; m < 4; ++m)                             \
        _Pragma("unroll") for (int r = 0; r < 4; ++r) acc[g2][m][r] *= fac;       \
      }                                                                           \
      f32x4 rsv = {0.f, 0.f, 0.f, 0.f};                                           \
      const float mneg = -m_run[g2] * Cs;                                         \
      _Pragma("unroll") for (int n = 0; n < 8; ++n)                               \
      _Pragma("unroll") for (int r = 0; r < 4; ++r) {                             \
        const float p = exp2f(fmaf(sc[g2][n][r], Cs, mneg));                      \
        sc[g2][n][r] = p;                                                         \
        rsv[r] += p;                                                              \
      }                                                                           \
      float rs = (rsv[0] + rsv[1]) + (rsv[2] + rsv[3]);                           \
      rs += __shfl_xor(rs, 16);                                                   \
      rs += __shfl_xor(rs, 32);                                                   \
      l_run[g2] += rs;                                                            \
      _Pragma("unroll") for (int n = 0; n < 8; ++n) {                             \
        asm("v_cvt_pk_bf16_f32 %0, %1, %2"                                        \
            : "=v"(pk[g2].u[2 * n]) : "v"(sc[g2][n][0]), "v"(sc[g2][n][1]));      \
        asm("v_cvt_pk_bf16_f32 %0, %1, %2"                                        \
            : "=v"(pk[g2].u[2 * n + 1]) : "v"(sc[g2][n][2]), "v"(sc[g2][n][3])); \
      }                                                                           \
    }                                                                             \
    _Pragma("unroll") for (int m = 0; m < 4; ++m) {                               \
      const u16* vr = vt + m * 2048;                                              \
      s16x8 vfr[4];                                                               \
      _Pragma("unroll") for (int c = 0; c < 4; ++c) {                             \
        union VF { s16x4 h[2]; s16x8 v; } vv;                                     \
        vv.h[0] = *reinterpret_cast<const s16x4*>(vr + vbase[2 * c]);             \
        vv.h[1] = *reinterpret_cast<const s16x4*>(vr + vbase[2 * c + 1]);         \
        vfr[c] = vv.v;                                                            \
      }                                                                           \
      __builtin_amdgcn_s_setprio(1);                                              \
      _Pragma("unroll") for (int c = 0; c < 4; ++c) {                             \
        acc[0][m] = MFMA16(vfr[c], pk[0].v[c], acc[0][m]);                        \
        acc[1][m] = MFMA16(vfr[c], pk[1].v[c], acc[1][m]);                        \
      }                                                                           \
      __builtin_amdgcn_s_setprio(0);                                              \
    }                                                                             \
    mcur0 = mnext0;                                                               \
    mcur1 = mnext1;                                                               \
  }

  for (int t = 0; t < NTT_; t += 2) {
    ATTN_TILE(t, 0)
    ATTN_TILE(t + 1, 1)
  }
#undef ATTN_TILE

  // normalize + store O^T -> O (bf16, token-major [BS][D])
#pragma unroll
  for (int g2 = 0; g2 < 2; ++g2) {
    const float rl = 1.0f / l_run[g2];
    u16* op = O + (size_t)(b * S_ + q0 + g2 * 16 + l16) * D_ + h * HD_ + kq * 4;
#pragma unroll
    for (int m = 0; m < 4; ++m) {
      uint2 o;
      o.x = (uint32_t)f2b(acc[g2][m][0] * rl) | ((uint32_t)f2b(acc[g2][m][1] * rl) << 16);
      o.y = (uint32_t)f2b(acc[g2][m][2] * rl) | ((uint32_t)f2b(acc[g2][m][3] * rl) << 16);
      *reinterpret_cast<uint2*>(op + m * 16) = o;
    }
  }
}

// ---------------- launch ----------------
extern "C" void kernel_launch(void* const* d_in, const int* in_sizes, int n_in,
                              void* d_out, int out_size, void* d_ws, size_t ws_size,
                              hipStream_t stream) {
  const float* x = (const float*)d_in[0];
  const int* mask = (const int*)d_in[1];
  const float* Wq = (const float*)d_in[2];
  const float* Wk = (const float*)d_in[3];
  const float* Wv = (const float*)d_in[4];
  const float* Wo = (const float*)d_in[5];

  char* w = (char*)d_ws;
  u16* xb = (u16*)w;    w += (size_t)BS_ * D_ * 2;     // contiguous cvt dst
  u16* Wqkvb = (u16*)w; w += (size_t)QKVS_ * D_ * 2;
  u16* Wob = (u16*)w;   w += (size_t)D_ * D_ * 2;
  u16* QKVw = (u16*)w;  w += (size_t)BS_ * QKVS_ * 2;
  u16* VTw = (u16*)w;   w += (size_t)B_ * KVH_ * HD_ * S_ * 2;
  u16* AOw = (u16*)w;   w += (size_t)BS_ * D_ * 2;

  const int n4tot = (BS_ * D_ + QKVS_ * D_ + D_ * D_) / 4;
  cvt5_kernel<<<dim3(2048), dim3(256), 0, stream>>>(x, Wq, Wk, Wv, Wo, xb, n4tot);

  // fused QKV projection (V cols written transposed to VTw): 768 blocks (3/CU)
  gemm64<1, 1><<<dim3(QKVS_ / 128, BS_ / 64), dim3(256), 0, stream>>>(
      xb, Wqkvb, QKVw, VTw, BS_, QKVS_, D_);
  // attention: (S/64, B*KVH) blocks of 8 waves, 64 q-rows/block, KVBLK=128
  attn_kernel<<<dim3(S_ / 64, B_ * KVH_), dim3(512), 0, stream>>>(QKVw, VTw, mask, AOw);
  // output projection -> fp32 d_out, 512 blocks (dbuf staging)
  gemm64<0, 0><<<dim3(D_ / 128, BS_ / 64), dim3(256), 0, stream>>>(
      AOw, Wob, (float*)d_out, nullptr, BS_, D_, D_);
}

// Round 23
// 112.131 us; speedup vs baseline: 2.2171x; 2.2171x over previous
//
#include <hip/hip_runtime.h>
#include <hip/hip_bf16.h>
#include <stdint.h>

// Problem constants (GroupedQueryAttention: B=2,S=2048,D=1024,H=16,KVH=4)
#define B_    2
#define S_    2048
#define D_    1024
#define H_    16
#define KVH_  4
#define HD_   64
#define REP_  4
#define BS_   (B_ * S_)        // 4096 tokens
#define KVD_  256
#define QKVS_ 1536             // fused QKV row stride: Q(1024) | K(256) | V(256)
#define NTT_  (S_ / 128)       // 16 KV tiles of 128
#define VSPLIT_ (D_ + KVD_)    // 1280: V columns start here (block-aligned)

typedef unsigned short u16;
typedef short s16x4 __attribute__((ext_vector_type(4)));
typedef short s16x8 __attribute__((ext_vector_type(8)));
typedef float f32x4 __attribute__((ext_vector_type(4)));

typedef const __attribute__((address_space(1))) void* gvp;
typedef __attribute__((address_space(3))) void* lvp;

#define MFMA16(a, b, c) __builtin_amdgcn_mfma_f32_16x16x32_bf16((a), (b), (c), 0, 0, 0)

__device__ __forceinline__ u16 f2b(float f) {  // RNE f32->bf16 (finite inputs)
  uint32_t u = __float_as_uint(f);
  u += 0x7fffu + ((u >> 16) & 1u);
  return (u16)(u >> 16);
}

// XOR swizzles: 64-wide rows (8 x 16B slots) and 128-wide rows (16 slots).
__device__ __forceinline__ int swz64(int row, int slot) {
  return slot ^ (row & 7) ^ ((row >> 3) & 7);
}
__device__ __forceinline__ int swz128(int row, int slot) {
  return slot ^ (row & 15);
}

// ---------------- fused f32 -> bf16 conversion over 5 segments ----------------
#define N0_ (BS_ * D_ / 4)
#define N1_ (D_ * D_ / 4)
#define N2_ (KVD_ * D_ / 4)
__global__ void cvt5_kernel(const float* __restrict__ s0, const float* __restrict__ s1,
                            const float* __restrict__ s2, const float* __restrict__ s3,
                            const float* __restrict__ s4, u16* __restrict__ dst, int n4tot) {
  for (int i = blockIdx.x * blockDim.x + threadIdx.x; i < n4tot;
       i += gridDim.x * blockDim.x) {
    const float* src;
    int j = i;
    if (j < N0_) src = s0;
    else if ((j -= N0_) < N1_) src = s1;
    else if ((j -= N1_) < N2_) src = s2;
    else if ((j -= N2_) < N2_) src = s3;
    else { j -= N2_; src = s4; }
    const float4 v = reinterpret_cast<const float4*>(src)[j];
    uint2 o;
    o.x = (uint32_t)f2b(v.x) | ((uint32_t)f2b(v.y) << 16);
    o.y = (uint32_t)f2b(v.z) | ((uint32_t)f2b(v.w) << 16);
    reinterpret_cast<uint2*>(dst)[i] = o;
  }
}

// ---------------- bf16 GEMM, C = A(MxK) * B(NxK)^T, 64x128 tile, BK=64 ----------------
// Double-buffered staging; swz64 both-sides LDS swizzle; XCD-bijective grid.
// WRITE_VT: V-columns (>= VSPLIT_) written TRANSPOSED to VT (fused vtrans).
template <int OUT_BF16, int WRITE_VT>
__global__ __launch_bounds__(256) void gemm64(const u16* __restrict__ A,
                                              const u16* __restrict__ Bw,
                                              void* __restrict__ Cout,
                                              u16* __restrict__ VT,
                                              int M, int N, int K) {
  __shared__ u16 As[2][64 * 64];
  __shared__ u16 Bs[2][128 * 64];
  const int tid = threadIdx.x;
  const int lane = tid & 63;
  const int wid = tid >> 6;
  const int l16 = lane & 15;
  const int kq = lane >> 4;
  // XCD swizzle: hw-blocks on one XCD (bid0 mod 8) get a contiguous logical chunk
  const int nwg = gridDim.x * gridDim.y;
  const int bid0 = blockIdx.y * gridDim.x + blockIdx.x;
  const int bid = (bid0 & 7) * (nwg >> 3) + (bid0 >> 3);
  const int bm = (bid / gridDim.x) * 64;
  const int bn = (bid % gridDim.x) * 128;
  const int wr = (wid >> 1) * 32;
  const int wc = (wid & 1) * 64;

  // staging geometry (pre-swizzled source cols, linear LDS dst)
  int arow[2], acol[2], brow[4], bcol[4], sdst[4];
#pragma unroll
  for (int i = 0; i < 4; ++i) {
    const int e = (i * 256 + tid) * 8;
    const int row = e >> 6;
    const int col = swz64(row, (e >> 3) & 7) * 8;
    sdst[i] = e;
    if (i < 2) { arow[i] = row; acol[i] = col; }
    brow[i] = row;
    bcol[i] = col;
  }
  // frag read offsets (involution)
  int aoff[2][2], boff[4][2];
#pragma unroll
  for (int m = 0; m < 2; ++m)
#pragma unroll
    for (int kk = 0; kk < 2; ++kk) {
      const int row = wr + m * 16 + l16;
      aoff[m][kk] = row * 64 + swz64(row, kk * 4 + kq) * 8;
    }
#pragma unroll
  for (int n = 0; n < 4; ++n)
#pragma unroll
    for (int kk = 0; kk < 2; ++kk) {
      const int row = wc + n * 16 + l16;
      boff[n][kk] = row * 64 + swz64(row, kk * 4 + kq) * 8;
    }

  auto stage = [&](int buf, int kt) {
#pragma unroll
    for (int i = 0; i < 2; ++i)
      __builtin_amdgcn_global_load_lds((gvp)(A + (size_t)(bm + arow[i]) * K + kt + acol[i]),
                                       (lvp)(&As[buf][sdst[i]]), 16, 0, 0);
#pragma unroll
    for (int i = 0; i < 4; ++i)
      __builtin_amdgcn_global_load_lds((gvp)(Bw + (size_t)(bn + brow[i]) * K + kt + bcol[i]),
                                       (lvp)(&Bs[buf][sdst[i]]), 16, 0, 0);
  };

  f32x4 acc[2][4] = {};
  stage(0, 0);
  int cur = 0;

  for (int kt = 0; kt < K; kt += 64) {
    __syncthreads();                   // buf[cur] ready (drains in-flight loads)
    if (kt + 64 < K) stage(cur ^ 1, kt + 64);

#pragma unroll
    for (int kk = 0; kk < 2; ++kk) {
      s16x8 af[2], bfr[4];
#pragma unroll
      for (int m = 0; m < 2; ++m)
        af[m] = *reinterpret_cast<const s16x8*>(&As[cur][aoff[m][kk]]);
#pragma unroll
      for (int n = 0; n < 4; ++n)
        bfr[n] = *reinterpret_cast<const s16x8*>(&Bs[cur][boff[n][kk]]);
#pragma unroll
      for (int m = 0; m < 2; ++m)
#pragma unroll
        for (int n = 0; n < 4; ++n)
          acc[m][n] = MFMA16(af[m], bfr[n], acc[m][n]);
    }
    cur ^= 1;
  }

  if (WRITE_VT && bn >= VSPLIT_) {
    // V block: write transposed to VT[((b*4+g)*64+d)][s]; 4 consecutive tokens
    // per (m,n) = 8B contiguous store.
#pragma unroll
    for (int m = 0; m < 2; ++m) {
      const int row0 = bm + wr + m * 16 + kq * 4;   // token row (4 consecutive)
      const int b = row0 >> 11;
      const int s = row0 & (S_ - 1);
#pragma unroll
      for (int n = 0; n < 4; ++n) {
        const int off = bn - VSPLIT_ + wc + n * 16 + l16;
        const int g = off >> 6;
        const int d = off & 63;
        uint2 o;
        o.x = (uint32_t)f2b(acc[m][n][0]) | ((uint32_t)f2b(acc[m][n][1]) << 16);
        o.y = (uint32_t)f2b(acc[m][n][2]) | ((uint32_t)f2b(acc[m][n][3]) << 16);
        *reinterpret_cast<uint2*>(&VT[((size_t)(b * 4 + g) * 64 + d) * S_ + s]) = o;
      }
    }
    return;
  }

#pragma unroll
  for (int m = 0; m < 2; ++m) {
    const int row0 = bm + wr + m * 16 + kq * 4;
#pragma unroll
    for (int n = 0; n < 4; ++n) {
      const int col = bn + wc + n * 16 + l16;
#pragma unroll
      for (int r = 0; r < 4; ++r) {
        if (OUT_BF16) {
          ((u16*)Cout)[(size_t)(row0 + r) * N + col] = f2b(acc[m][n][r]);
        } else {
          ((float*)Cout)[(size_t)(row0 + r) * N + col] = acc[m][n][r];
        }
      }
    }
  }
}

// ---------------- flash attention (GQA): zero-shuffle PV, KVBLK=128, 8 waves ----------------
// 512 thr = 8 waves: wave w = (q-sub w>>2, head g*4+(w&3)), 64 q-rows/block.
// K/V staging shared by 8 waves; grid 256 blocks; LDS 64KB -> 2 blocks/CU ->
// 16 waves/CU = 4 waves/SIMD. NO min-occupancy launch-bounds arg (r22's
// forced 64-VGPR cap caused catastrophic scratch spills).
__global__ __launch_bounds__(512) void attn_kernel(const u16* __restrict__ QKV,
                                                   const u16* __restrict__ VT,
                                                   const int* __restrict__ mask,
                                                   u16* __restrict__ O) {
  __shared__ u16 Ks[2][128 * 64];      // K rows, 64-wide swizzled
  __shared__ u16 Vt[2][64 * 128];      // V^T rows (d), 128-wide swizzled

  const int tid = threadIdx.x;
  const int lane = tid & 63;
  const int wid = tid >> 6;            // 0..7
  const int l16 = lane & 15;
  const int kq = lane >> 4;            // 0..3
  const int bg = blockIdx.y;
  const int b = bg >> 2;               // / KVH
  const int g = bg & 3;
  const int h = g * REP_ + (wid & 3);
  const int q0 = blockIdx.x * 64 + (wid >> 2) * 32;
  const u16* kv_base = QKV + (size_t)b * S_ * QKVS_ + D_ + g * HD_;  // K cols
  const u16* vt_base = VT + (size_t)bg * 64 * S_;                     // V^T rows
  const int* maskp = mask + b * S_ + lane;
  const float Cs = 0.18033688011112042f;  // SCALE * log2(e)

  // ---- precomputed per-thread LDS element offsets (loop-invariant) ----
  int koff[8][2];
#pragma unroll
  for (int n = 0; n < 8; ++n)
#pragma unroll
    for (int c = 0; c < 2; ++c) {
      const int row = n * 16 + l16;
      koff[n][c] = row * 64 + swz64(row, c * 4 + kq) * 8;
    }
  const int hs = kq >> 1;
  const int bo = 4 * (kq & 1);
  int vbase[8];                        // voff = vbase[j] + m*2048  (drow&15 == l16)
#pragma unroll
  for (int c = 0; c < 4; ++c) {
    vbase[2 * c] = l16 * 128 + swz128(l16, 4 * c + hs) * 8 + bo;
    vbase[2 * c + 1] = l16 * 128 + swz128(l16, 4 * c + 2 + hs) * 8 + bo;
  }
  // staging: 512 threads x 2 iters x 8 elems = 8192 elems per buffer
  int kst_src[2], vst_src[2], st_dst[2];
#pragma unroll
  for (int i = 0; i < 2; ++i) {
    const int e = (i * 512 + tid) * 8;
    st_dst[i] = e;
    const int krow = e >> 6;
    kst_src[i] = krow * QKVS_ + swz64(krow, (e >> 3) & 7) * 8;   // + kv0*QKVS_
    const int vrow = e >> 7;
    vst_src[i] = vrow * S_ + swz128(vrow, (e >> 3) & 15) * 8;    // + kv0
  }

  auto kstage = [&](int buf, int kv0) {
#pragma unroll
    for (int i = 0; i < 2; ++i)
      __builtin_amdgcn_global_load_lds(
          (gvp)(kv_base + (size_t)kv0 * QKVS_ + kst_src[i]),
          (lvp)(&Ks[buf][st_dst[i]]), 16, 0, 0);
  };
  auto vstage = [&](int buf, int kv0) {
#pragma unroll
    for (int i = 0; i < 2; ++i)
      __builtin_amdgcn_global_load_lds(
          (gvp)(vt_base + kv0 + vst_src[i]),
          (lvp)(&Vt[buf][st_dst[i]]), 16, 0, 0);
  };

  // Q B-frags: qf[g2][c] = Q[q0+g2*16+l16][c*32+kq*8..]
  s16x8 qf[2][2];
#pragma unroll
  for (int g2 = 0; g2 < 2; ++g2) {
    const u16* qp = QKV + (size_t)(b * S_ + q0 + g2 * 16 + l16) * QKVS_ + h * HD_ + kq * 8;
    qf[g2][0] = *reinterpret_cast<const s16x8*>(qp);
    qf[g2][1] = *reinterpret_cast<const s16x8*>(qp + 32);
  }

  // prologue: stage tile 0 into buf 0; mask tile 0 into regs
  kstage(0, 0);
  vstage(0, 0);
  int mcur0 = maskp[0];
  int mcur1 = maskp[64];

  float m_run[2] = {-1e30f, -1e30f}, l_run[2] = {0.f, 0.f};
  f32x4 acc[2][4] = {};                // O^T per group: row d=m*16+kq*4+r, col q=l16

#define ATTN_TILE(T_, BUF_)                                                       \
  {                                                                               \
    const int t_ = (T_);                                                          \
    __syncthreads();                                                              \
    const bool pfch = (t_ + 1 < NTT_);                                            \
    int mnext0 = 0, mnext1 = 0;                                                   \
    if (pfch) {                                                                   \
      kstage((BUF_) ^ 1, (t_ + 1) * 128);                                         \
      vstage((BUF_) ^ 1, (t_ + 1) * 128);                                         \
      mnext0 = maskp[(t_ + 1) * 128];                                             \
      mnext1 = maskp[(t_ + 1) * 128 + 64];                                        \
    }                                                                             \
    const u16* ks = &Ks[(BUF_)][0];                                               \
    const u16* vt = &Vt[(BUF_)][0];                                               \
    f32x4 sc[2][8];                                                               \
    __builtin_amdgcn_s_setprio(1);                                                \
    _Pragma("unroll") for (int n = 0; n < 8; ++n) {                               \
      const s16x8 kf0 = *reinterpret_cast<const s16x8*>(ks + koff[n][0]);         \
      const s16x8 kf1 = *reinterpret_cast<const s16x8*>(ks + koff[n][1]);         \
      f32x4 s0 = {0.f, 0.f, 0.f, 0.f};                                            \
      f32x4 s1 = {0.f, 0.f, 0.f, 0.f};                                            \
      s0 = MFMA16(kf0, qf[0][0], s0);                                             \
      s1 = MFMA16(kf0, qf[1][0], s1);                                             \
      s0 = MFMA16(kf1, qf[0][1], s0);                                             \
      s1 = MFMA16(kf1, qf[1][1], s1);                                             \
      sc[0][n] = s0;                                                              \
      sc[1][n] = s1;                                                              \
    }                                                                             \
    __builtin_amdgcn_s_setprio(0);                                                \
    const unsigned long long mb0 = __ballot(mcur0 != 0);                          \
    const unsigned long long mb1 = __ballot(mcur1 != 0);                          \
    if ((~mb0) | (~mb1)) {                                                        \
      _Pragma("unroll") for (int n = 0; n < 8; ++n) {                             \
        const unsigned long long mb = (n < 4) ? mb0 : mb1;                        \
        const int sh = (n & 3) * 16 + kq * 4;                                     \
        _Pragma("unroll") for (int r = 0; r < 4; ++r) {                           \
          if (!((mb >> (sh + r)) & 1ull)) {                                       \
            sc[0][n][r] = -3.0e38f;                                               \
            sc[1][n][r] = -3.0e38f;                                               \
          }                                                                       \
        }                                                                         \
      }                                                                           \
    }                                                                             \
    union PK { uint32_t u[16]; s16x8 v[4]; } pk[2];                               \
    _Pragma("unroll") for (int g2 = 0; g2 < 2; ++g2) {                            \
      f32x4 tv = sc[g2][0];                                                       \
      _Pragma("unroll") for (int n = 1; n < 8; ++n) {                             \
        tv[0] = fmaxf(tv[0], sc[g2][n][0]);                                       \
        tv[1] = fmaxf(tv[1], sc[g2][n][1]);                                       \
        tv[2] = fmaxf(tv[2], sc[g2][n][2]);                                       \
        tv[3] = fmaxf(tv[3], sc[g2][n][3]);                                       \
      }                                                                           \
      float tm = fmaxf(fmaxf(tv[0], tv[1]), fmaxf(tv[2], tv[3]));                 \
      tm = fmaxf(tm, __shfl_xor(tm, 16));                                         \
      tm = fmaxf(tm, __shfl_xor(tm, 32));                                         \
      if (!__all(tm <= m_run[g2] + 44.0f)) {                                      \
        const float mnew = fmaxf(m_run[g2], tm);                                  \
        const float fac = exp2f((m_run[g2] - mnew) * Cs);                         \
        m_run[g2] = mnew;                                                         \
        l_run[g2] *= fac;                                                         \
        _Pragma("unroll") for (int m = 0; m < 4; ++m)                             \
        _Pragma("unroll") for (int r = 0; r < 4; ++r) acc[g2][m][r] *= fac;       \
      }                                                                           \
      f32x4 rsv = {0.f, 0.f, 0.f, 0.f};                                           \
      const float mneg = -m_run[g2] * Cs;                                         \
      _Pragma("unroll") for (int n = 0; n < 8; ++n)                               \
      _Pragma("unroll") for (int r = 0; r < 4; ++r) {                             \
        const float p = exp2f(fmaf(sc[g2][n][r], Cs, mneg));                      \
        sc[g2][n][r] = p;                                                         \
        rsv[r] += p;                                                              \
      }                                                                           \
      float rs = (rsv[0] + rsv[1]) + (rsv[2] + rsv[3]);                           \
      rs += __shfl_xor(rs, 16);                                                   \
      rs += __shfl_xor(rs, 32);                                                   \
      l_run[g2] += rs;                                                            \
      _Pragma("unroll") for (int n = 0; n < 8; ++n) {                             \
        asm("v_cvt_pk_bf16_f32 %0, %1, %2"                                        \
            : "=v"(pk[g2].u[2 * n]) : "v"(sc[g2][n][0]), "v"(sc[g2][n][1]));      \
        asm("v_cvt_pk_bf16_f32 %0, %1, %2"                                        \
            : "=v"(pk[g2].u[2 * n + 1]) : "v"(sc[g2][n][2]), "v"(sc[g2][n][3])); \
      }                                                                           \
    }                                                                             \
    _Pragma("unroll") for (int m = 0; m < 4; ++m) {                               \
      const u16* vr = vt + m * 2048;                                              \
      s16x8 vfr[4];                                                               \
      _Pragma("unroll") for (int c = 0; c < 4; ++c) {                             \
        union VF { s16x4 h[2]; s16x8 v; } vv;                                     \
        vv.h[0] = *reinterpret_cast<const s16x4*>(vr + vbase[2 * c]);             \
        vv.h[1] = *reinterpret_cast<const s16x4*>(vr + vbase[2 * c + 1]);         \
        vfr[c] = vv.v;                                                            \
      }                                                                           \
      __builtin_amdgcn_s_setprio(1);                                              \
      _Pragma("unroll") for (int c = 0; c < 4; ++c) {                             \
        acc[0][m] = MFMA16(vfr[c], pk[0].v[c], acc[0][m]);                        \
        acc[1][m] = MFMA16(vfr[c], pk[1].v[c], acc[1][m]);                        \
      }                                                                           \
      __builtin_amdgcn_s_setprio(0);                                              \
    }                                                                             \
    mcur0 = mnext0;                                                               \
    mcur1 = mnext1;                                                               \
  }

  for (int t = 0; t < NTT_; t += 2) {
    ATTN_TILE(t, 0)
    ATTN_TILE(t + 1, 1)
  }
#undef ATTN_TILE

  // normalize + store O^T -> O (bf16, token-major [BS][D])
#pragma unroll
  for (int g2 = 0; g2 < 2; ++g2) {
    const float rl = 1.0f / l_run[g2];
    u16* op = O + (size_t)(b * S_ + q0 + g2 * 16 + l16) * D_ + h * HD_ + kq * 4;
#pragma unroll
    for (int m = 0; m < 4; ++m) {
      uint2 o;
      o.x = (uint32_t)f2b(acc[g2][m][0] * rl) | ((uint32_t)f2b(acc[g2][m][1] * rl) << 16);
      o.y = (uint32_t)f2b(acc[g2][m][2] * rl) | ((uint32_t)f2b(acc[g2][m][3] * rl) << 16);
      *reinterpret_cast<uint2*>(op + m * 16) = o;
    }
  }
}

// ---------------- launch ----------------
extern "C" void kernel_launch(void* const* d_in, const int* in_sizes, int n_in,
                              void* d_out, int out_size, void* d_ws, size_t ws_size,
                              hipStream_t stream) {
  const float* x = (const float*)d_in[0];
  const int* mask = (const int*)d_in[1];
  const float* Wq = (const float*)d_in[2];
  const float* Wk = (const float*)d_in[3];
  const float* Wv = (const float*)d_in[4];
  const float* Wo = (const float*)d_in[5];

  char* w = (char*)d_ws;
  u16* xb = (u16*)w;    w += (size_t)BS_ * D_ * 2;     // contiguous cvt dst
  u16* Wqkvb = (u16*)w; w += (size_t)QKVS_ * D_ * 2;
  u16* Wob = (u16*)w;   w += (size_t)D_ * D_ * 2;
  u16* QKVw = (u16*)w;  w += (size_t)BS_ * QKVS_ * 2;
  u16* VTw = (u16*)w;   w += (size_t)B_ * KVH_ * HD_ * S_ * 2;
  u16* AOw = (u16*)w;   w += (size_t)BS_ * D_ * 2;

  const int n4tot = (BS_ * D_ + QKVS_ * D_ + D_ * D_) / 4;
  cvt5_kernel<<<dim3(2048), dim3(256), 0, stream>>>(x, Wq, Wk, Wv, Wo, xb, n4tot);

  // fused QKV projection (V cols written transposed to VTw): 768 blocks (3/CU)
  gemm64<1, 1><<<dim3(QKVS_ / 128, BS_ / 64), dim3(256), 0, stream>>>(
      xb, Wqkvb, QKVw, VTw, BS_, QKVS_, D_);
  // attention: (S/64, B*KVH) blocks of 8 waves, 64 q-rows/block, KVBLK=128
  attn_kernel<<<dim3(S_ / 64, B_ * KVH_), dim3(512), 0, stream>>>(QKVw, VTw, mask, AOw);
  // output projection -> fp32 d_out, 512 blocks (dbuf staging)
  gemm64<0, 0><<<dim3(D_ / 128, BS_ / 64), dim3(256), 0, stream>>>(
      AOw, Wob, (float*)d_out, nullptr, BS_, D_, D_);
}